// Round 1
// baseline (323.563 us; speedup 1.0000x reference)
//
#include <hip/hip_runtime.h>

// Soft-argmax over channel groups:
//   x_in: (4, 14, 1024, 1024) fp32 NCHW
//   out:  (4, 2, 1024, 1024)  fp32 NCHW
//   out[b,o,h,w] = sum_k softmax_k(x[b, o*7+k, h, w]) * (k - 3)
//
// HBM-bound: 235 MB in + 33.5 MB out => ~43 us floor at 6.3 TB/s.
// One thread = 4 contiguous pixels (float4); 14 coalesced plane loads,
// 2 float4 stores. All channel/batch strides are powers of two (HW = 2^20).

#define HW_LOG2 20          // H*W = 1024*1024
#define HW4_LOG2 18         // (H*W)/4 in float4 units
#define C_IN 14
#define K 7
#define OC 2

__global__ __launch_bounds__(256) void softargmax_kernel(
    const float4* __restrict__ x, float4* __restrict__ out, int n4)
{
    int tid = blockIdx.x * blockDim.x + threadIdx.x;
    if (tid >= n4) return;

    const int b   = tid >> HW4_LOG2;                 // batch index (0..3)
    const int sp4 = tid & ((1 << HW4_LOG2) - 1);     // spatial float4 index

    // Base of this batch's first channel plane, in float4 units.
    const float4* __restrict__ src = x + (((long long)b * C_IN) << HW4_LOG2) + sp4;

    // Load all 14 channel values for the 4 pixels. v[c][j] = channel c, pixel j.
    float v[C_IN][4];
    #pragma unroll
    for (int c = 0; c < C_IN; ++c) {
        float4 t = src[(long long)c << HW4_LOG2];
        v[c][0] = t.x; v[c][1] = t.y; v[c][2] = t.z; v[c][3] = t.w;
    }

    float4* __restrict__ dst = out + (((long long)b * OC) << HW4_LOG2) + sp4;

    #pragma unroll
    for (int o = 0; o < OC; ++o) {
        float4 res;
        float* r = reinterpret_cast<float*>(&res);
        #pragma unroll
        for (int j = 0; j < 4; ++j) {
            // stabilized softmax weighted sum over K=7, weights (k-3)
            float m = v[o * K + 0][j];
            #pragma unroll
            for (int k = 1; k < K; ++k) m = fmaxf(m, v[o * K + k][j]);
            float num = 0.0f, den = 0.0f;
            #pragma unroll
            for (int k = 0; k < K; ++k) {
                float e = __expf(v[o * K + k][j] - m);
                num = fmaf(e, (float)(k - 3), num);
                den += e;
            }
            r[j] = num / den;
        }
        dst[(long long)o << HW4_LOG2] = res;
    }
}

extern "C" void kernel_launch(void* const* d_in, const int* in_sizes, int n_in,
                              void* d_out, int out_size, void* d_ws, size_t ws_size,
                              hipStream_t stream) {
    const float4* x = (const float4*)d_in[0];
    float4* out = (float4*)d_out;
    // total spatial float4 groups: B * H * W / 4 = 4 * 2^20 / 4 = 2^20
    const int n4 = in_sizes[0] / (C_IN * 4);
    const int block = 256;
    const int grid = (n4 + block - 1) / block;
    softargmax_kernel<<<grid, block, 0, stream>>>(x, out, n4);
}

// Round 3
// 304.526 us; speedup vs baseline: 1.0625x; 1.0625x over previous
//
#include <hip/hip_runtime.h>

// Soft-argmax over channel groups:
//   x_in: (4, 14, 1024, 1024) fp32 NCHW
//   out:  (4, 2, 1024, 1024)  fp32 NCHW
//   out[b,o,h,w] = sum_k softmax_k(x[b, o*7+k, h, w]) * (k - 3)
//
// HBM-bound: 235 MB in + 33.5 MB out => ~43 us floor at 6.3 TB/s.
// One thread = one output group = 4 contiguous pixels of ONE output channel
// (7 plane loads + 1 store). Nontemporal hints: pure streaming, zero reuse.
// NOTE: nontemporal builtins need a NATIVE vector type, not HIP float4.

#define HW4_LOG2 18         // (H*W)/4 in float4 units
#define K 7

typedef float f32x4 __attribute__((ext_vector_type(4)));

__global__ __launch_bounds__(256) void softargmax_kernel(
    const f32x4* __restrict__ x, f32x4* __restrict__ out, int n)
{
    int tid = blockIdx.x * blockDim.x + threadIdx.x;
    if (tid >= n) return;

    const int g   = tid >> HW4_LOG2;                 // b*2 + o  (0..7)
    const int sp4 = tid & ((1 << HW4_LOG2) - 1);     // spatial float4 index

    // input plane index of this group's first channel: b*14 + o*7 = 7*g
    const f32x4* __restrict__ src = x + (((long long)(7 * g)) << HW4_LOG2) + sp4;

    // Load all 7 channel values for the 4 pixels. v[k] = channel k (4 pixels).
    f32x4 v[K];
    #pragma unroll
    for (int k = 0; k < K; ++k)
        v[k] = __builtin_nontemporal_load(&src[(long long)k << HW4_LOG2]);

    f32x4 res;
    #pragma unroll
    for (int j = 0; j < 4; ++j) {
        // stabilized softmax weighted sum over K=7, weights (k-3)
        float m = v[0][j];
        #pragma unroll
        for (int k = 1; k < K; ++k) m = fmaxf(m, v[k][j]);
        float num = 0.0f, den = 0.0f;
        #pragma unroll
        for (int k = 0; k < K; ++k) {
            float e = __expf(v[k][j] - m);
            num = fmaf(e, (float)(k - 3), num);
            den += e;
        }
        res[j] = num / den;
    }
    // output plane index = b*2 + o = g
    __builtin_nontemporal_store(res, &out[(((long long)g) << HW4_LOG2) + sp4]);
}

extern "C" void kernel_launch(void* const* d_in, const int* in_sizes, int n_in,
                              void* d_out, int out_size, void* d_ws, size_t ws_size,
                              hipStream_t stream) {
    const f32x4* x = (const f32x4*)d_in[0];
    f32x4* out = (f32x4*)d_out;
    // one thread per (batch, out_channel, float4-group): B*2*HW/4 = in_sizes[0]/28
    const int n = in_sizes[0] / (K * 4);
    const int block = 256;
    const int grid = (n + block - 1) / block;
    softargmax_kernel<<<grid, block, 0, stream>>>(x, out, n);
}